// Round 10
// baseline (220.770 us; speedup 1.0000x reference)
//
#include <hip/hip_runtime.h>

#define DEV __device__ __forceinline__

typedef __bf16 bf16_t;
typedef bf16_t bf16x8 __attribute__((ext_vector_type(8)));
typedef float f32x4 __attribute__((ext_vector_type(4)));

static constexpr int VOCAB = 32000, DIM = 1024, BATCH = 64, SEQ = 512;
static constexpr int M_SC = BATCH * SEQ;  // 32768

DEV unsigned short f2bf(float f) {
  unsigned u = __builtin_bit_cast(unsigned, f);
  u += 0x7FFFu + ((u >> 16) & 1u);  // RNE, inputs are finite
  return (unsigned short)(u >> 16);
}

DEV float sigmf(float x) {
  x = fminf(fmaxf(x, -30.f), 30.f);
  return 1.0f / (1.0f + __expf(-x));
}

DEV float tanh_fast(float x) {
  x = fminf(fmaxf(x, -20.f), 20.f);
  float e = __expf(2.0f * x);
  return (e - 1.0f) / (e + 1.0f);
}

DEV void gload_lds16(const void* g, void* l) {
  __builtin_amdgcn_global_load_lds(
      (__attribute__((address_space(1))) void*)(g),
      (__attribute__((address_space(3))) void*)(l), 16, 0, 0);
}

// ---------------- small prep: W1 -> bf16, zero att, embed gather ------------
__global__ void __launch_bounds__(256) k_small(const float* __restrict__ w1,
                                               unsigned short* __restrict__ w1_b,
                                               float* __restrict__ att_l,
                                               const int* __restrict__ x,
                                               const float* __restrict__ Femb,
                                               const float* __restrict__ h,
                                               float* __restrict__ emb_f,
                                               unsigned short* __restrict__ eh_b,
                                               unsigned short* __restrict__ h_b) {
  if (blockIdx.x >= 960) {  // last 64 blocks: embedding gather
    int b = blockIdx.x - 960;
    int tok = x[b];
    for (int d = threadIdx.x; d < DIM; d += 256) {
      float e = Femb[(size_t)tok * DIM + d];
      float hv = h[b * DIM + d];
      emb_f[b * DIM + d] = e;
      unsigned short eb = f2bf(e), hb = f2bf(hv);
      eh_b[b * 2 * DIM + d] = eb;
      eh_b[b * 2 * DIM + DIM + d] = hb;
      h_b[b * DIM + d] = hb;
    }
  }
  int gid = blockIdx.x * 256 + threadIdx.x;  // grid 1024 -> 262144 = DIM*DIM/4
  if (gid < M_SC) att_l[gid] = 0.f;
  float4 v = ((const float4*)w1)[gid];
  ushort4 o;
  o.x = f2bf(v.x); o.y = f2bf(v.y); o.z = f2bf(v.z); o.w = f2bf(v.w);
  *(ushort4*)(w1_b + (size_t)gid * 4) = o;
}

// ---------------- skinny GEMM: C[64 x N] = A(bf16) . W(f32,[*][1024])^T -----
__global__ void __launch_bounds__(256) k_skinny(
    const unsigned short* __restrict__ A, int lda,
    const float* __restrict__ B1, const float* __restrict__ B2, int ksplit,
    const float* __restrict__ bias, float* __restrict__ C, int N, int K) {
  __shared__ unsigned short As[2][64 * 128];
  __shared__ unsigned short Bs[2][16 * 128];
  int t = threadIdx.x;
  int l = t & 63, w = t >> 6;
  int n0 = blockIdx.x * 16;
  f32x4 acc = {};
  int rx = (l & 7) << 3;  // read-side XOR (elems)

  float4 vB[2];

  auto loadB = [&](int k0) {
    const float* Bsrc;
    int kk;
    if (k0 < ksplit) { Bsrc = B1; kk = k0; } else { Bsrc = B2; kk = k0 - ksplit; }
#pragma unroll
    for (int i = 0; i < 2; ++i) {
      int lin = i * 256 + t;
      int row = lin >> 5, c4 = (lin & 31) * 4;
      vB[i] = *(const float4*)(Bsrc + (size_t)(n0 + row) * 1024 + kk + c4);
    }
  };
  auto writeB = [&](int bufi) {
#pragma unroll
    for (int i = 0; i < 2; ++i) {
      int lin = i * 256 + t;
      int row = lin >> 5, c4 = (lin & 31) * 4;
      ushort4 o;
      o.x = f2bf(vB[i].x); o.y = f2bf(vB[i].y); o.z = f2bf(vB[i].z); o.w = f2bf(vB[i].w);
      *(ushort4*)&Bs[bufi][row * 128 + (c4 ^ ((row & 7) << 3))] = o;
    }
  };
  auto stageA = [&](int k0, int bufi) {
#pragma unroll
    for (int i = 0; i < 4; ++i) {
      int sbase = i * 256 + w * 64;       // wave-uniform 16B-slot base
      int s = sbase + l;
      int row = s >> 4;                   // 16 slots per 128-elem row
      int scol = ((s & 15) ^ (row & 7)) * 8;
      gload_lds16(A + (size_t)row * lda + k0 + scol, &As[bufi][sbase * 8]);
    }
  };
  auto compute = [&](int bufi) {
#pragma unroll
    for (int kf = 0; kf < 4; ++kf) {
      int ko = kf * 32 + 8 * (l >> 4);
      int ar = w * 16 + (l & 15);
      bf16x8 af = *(const bf16x8*)&As[bufi][ar * 128 + (ko ^ rx)];
      bf16x8 bf = *(const bf16x8*)&Bs[bufi][(l & 15) * 128 + (ko ^ rx)];
      acc = __builtin_amdgcn_mfma_f32_16x16x32_bf16(af, bf, acc, 0, 0, 0);
    }
  };

  loadB(0);
  stageA(0, 0);
  writeB(0);
  asm volatile("s_waitcnt lgkmcnt(0)" ::: "memory");

  int nk = K / 128;
  int cur = 0;
  for (int kt = 0; kt < nk - 1; ++kt) {
    loadB((kt + 1) * 128);
    stageA((kt + 1) * 128, cur ^ 1);
    asm volatile("s_waitcnt vmcnt(6)\n\ts_barrier" ::: "memory");
    compute(cur);
    writeB(cur ^ 1);
    asm volatile("s_waitcnt lgkmcnt(0)\n\ts_barrier" ::: "memory");
    cur ^= 1;
  }
  asm volatile("s_waitcnt vmcnt(0)\n\ts_barrier" ::: "memory");
  compute(cur);

  int cn = n0 + (l & 15);
  float bv = bias ? bias[cn] : 0.f;
#pragma unroll
  for (int r = 0; r < 4; ++r) {
    int m = w * 16 + (l >> 4) * 4 + r;
    C[(size_t)m * N + cn] = acc[r] + bv;
  }
}

// ---------------- skinny GEMM, N-tile 32 (for logits) -----------------------
__global__ void __launch_bounds__(256) k_skinny32(
    const unsigned short* __restrict__ A,
    const float* __restrict__ B, const float* __restrict__ bias,
    float* __restrict__ C, int N, int K) {
  __shared__ unsigned short As[2][64 * 128];
  __shared__ unsigned short Bs[2][32 * 128];
  int t = threadIdx.x;
  int l = t & 63, w = t >> 6;
  int n0 = blockIdx.x * 32;
  f32x4 acc0 = {}, acc1 = {};
  int rx = (l & 7) << 3;

  float4 vB[4];

  auto loadB = [&](int k0) {
#pragma unroll
    for (int i = 0; i < 4; ++i) {
      int lin = i * 256 + t;
      int row = lin >> 5, c4 = (lin & 31) * 4;
      vB[i] = *(const float4*)(B + (size_t)(n0 + row) * 1024 + k0 + c4);
    }
  };
  auto writeB = [&](int bufi) {
#pragma unroll
    for (int i = 0; i < 4; ++i) {
      int lin = i * 256 + t;
      int row = lin >> 5, c4 = (lin & 31) * 4;
      ushort4 o;
      o.x = f2bf(vB[i].x); o.y = f2bf(vB[i].y); o.z = f2bf(vB[i].z); o.w = f2bf(vB[i].w);
      *(ushort4*)&Bs[bufi][row * 128 + (c4 ^ ((row & 7) << 3))] = o;
    }
  };
  auto stageA = [&](int k0, int bufi) {
#pragma unroll
    for (int i = 0; i < 4; ++i) {
      int sbase = i * 256 + w * 64;
      int s = sbase + l;
      int row = s >> 4;
      int scol = ((s & 15) ^ (row & 7)) * 8;
      gload_lds16(A + (size_t)row * DIM + k0 + scol, &As[bufi][sbase * 8]);
    }
  };
  auto compute = [&](int bufi) {
#pragma unroll
    for (int kf = 0; kf < 4; ++kf) {
      int ko = kf * 32 + 8 * (l >> 4);
      int ar = w * 16 + (l & 15);
      bf16x8 af = *(const bf16x8*)&As[bufi][ar * 128 + (ko ^ rx)];
      bf16x8 b0 = *(const bf16x8*)&Bs[bufi][(l & 15) * 128 + (ko ^ rx)];
      bf16x8 b1 = *(const bf16x8*)&Bs[bufi][((l & 15) + 16) * 128 + (ko ^ rx)];
      acc0 = __builtin_amdgcn_mfma_f32_16x16x32_bf16(af, b0, acc0, 0, 0, 0);
      acc1 = __builtin_amdgcn_mfma_f32_16x16x32_bf16(af, b1, acc1, 0, 0, 0);
    }
  };

  loadB(0);
  stageA(0, 0);
  writeB(0);
  asm volatile("s_waitcnt lgkmcnt(0)" ::: "memory");

  int nk = K / 128;
  int cur = 0;
  for (int kt = 0; kt < nk - 1; ++kt) {
    loadB((kt + 1) * 128);
    stageA((kt + 1) * 128, cur ^ 1);
    asm volatile("s_waitcnt vmcnt(8)\n\ts_barrier" ::: "memory");
    compute(cur);
    writeB(cur ^ 1);
    asm volatile("s_waitcnt lgkmcnt(0)\n\ts_barrier" ::: "memory");
    cur ^= 1;
  }
  asm volatile("s_waitcnt vmcnt(0)\n\ts_barrier" ::: "memory");
  compute(cur);

  int cn = n0 + (l & 15);
  float bv0 = bias ? bias[cn] : 0.f;
  float bv1 = bias ? bias[cn + 16] : 0.f;
#pragma unroll
  for (int r = 0; r < 4; ++r) {
    int m = w * 16 + (l >> 4) * 4 + r;
    C[(size_t)m * N + cn] = acc0[r] + bv0;
    C[(size_t)m * N + cn + 16] = acc1[r] + bv1;
  }
}

// ---------------- big fused score GEMM: 8-phase 256x256, fp32-A in-kernel ----
// R6 skeleton (verified 89us) with A's gload_lds replaced by T14 reg-staging
// of fp32 enc (cvt->bf16->swizzled ds_write). B staging/barriers/MFMA order
// unchanged. A row sets: E = rows {0-63, 128-191} (read by MFMA_Q(0,*)),
// O = rows {64-127, 192-255} (read by MFMA_Q(1,*)). loadE/loadO at P1/P2
// (2-phase lead), writeE/writeO at P3/P4 (where R6 staged A anyway).
// FIFO: one explicit vmcnt(6) at P1 (retires b1' of prev iter); P3/P4
// writes carry reg-dep vmcnt(8)/vmcnt(2); never drains to 0 mid-loop.
#define READ_A(MH)                                                              \
  do {                                                                          \
    _Pragma("unroll") for (int mf = 0; mf < 4; ++mf)                            \
    _Pragma("unroll") for (int kk = 0; kk < 2; ++kk) {                          \
      int row_ = wm * 128 + (MH) * 64 + mf * 16 + lm;                           \
      fa[mf][kk] = *(const bf16x8*)&As[ct][row_ * 64 + ((kk * 32 + 8 * lq) ^ rx)]; \
    }                                                                           \
  } while (0)
#define READ_B(NH)                                                              \
  do {                                                                          \
    _Pragma("unroll") for (int nf = 0; nf < 2; ++nf)                            \
    _Pragma("unroll") for (int kk = 0; kk < 2; ++kk) {                          \
      int row_ = wn * 64 + (NH) * 32 + nf * 16 + lm;                            \
      fb[NH][nf][kk] = *(const bf16x8*)&Bs[ct][row_ * 64 + ((kk * 32 + 8 * lq) ^ rx)]; \
    }                                                                           \
  } while (0)
#define MFMA_Q(MH, NH)                                                          \
  do {                                                                          \
    __builtin_amdgcn_s_setprio(1);                                              \
    _Pragma("unroll") for (int mf = 0; mf < 4; ++mf)                            \
    _Pragma("unroll") for (int nf = 0; nf < 2; ++nf)                            \
    _Pragma("unroll") for (int kk = 0; kk < 2; ++kk)                            \
        acc[(MH) * 4 + mf][(NH) * 2 + nf] = __builtin_amdgcn_mfma_f32_16x16x32_bf16( \
            fa[mf][kk], fb[NH][nf][kk], acc[(MH) * 4 + mf][(NH) * 2 + nf], 0, 0, 0); \
    __builtin_amdgcn_s_setprio(0);                                              \
  } while (0)

__global__ void __launch_bounds__(512, 1) k_score(
    const float* __restrict__ enc, const unsigned short* __restrict__ w1mat,
    const float* __restrict__ js, const float* __restrict__ w1bias,
    const float* __restrict__ vw, float* __restrict__ att_l) {
  __shared__ unsigned short As[2][256 * 64];  // 2 x 32 KB
  __shared__ unsigned short Bs[2][256 * 64];  // 2 x 32 KB
  int tid = threadIdx.x;
  int lane = tid & 63, wid = tid >> 6;
  int wm = wid >> 2, wn = wid & 3;   // 2 x 4 wave grid
  int lm = lane & 15, lq = lane >> 4;
  int rx = (lane & 7) << 3;          // read-side XOR (elems)

  int wg = blockIdx.x;               // 512 blocks (%8==0, bijective)
  int swz = (wg & 7) * 64 + (wg >> 3);
  int m0 = (swz >> 2) * 256;         // XCD i owns m-tiles [i*16,(i+1)*16)
  int n0 = (swz & 3) * 256;          // n fastest -> A slab L2-shared in XCD

  const float* pa = enc + (size_t)m0 * DIM;
  const unsigned short* pb = w1mat + (size_t)n0 * DIM;

  f32x4 acc[8][4] = {};
  bf16x8 fa[4][2];       // current A half (mh), [mf][kk]
  bf16x8 fb[2][2][2];    // both B halves,   [nh][nf][kk]

  // A reg-staging geometry: thread covers 16 consecutive f32 of one row.
  int ar4 = tid >> 2;                    // row-in-set 0..127
  int ac = (tid & 3) * 16;               // col f32
  int grE = (ar4 & 63) + ((ar4 >> 6) << 7);  // E rows: 0-63, 128-191
  float4 vAE[4], vAO[4];

  auto loadE = [&](int kt) {
    const float* s = pa + (size_t)grE * DIM + kt * 64 + ac;
#pragma unroll
    for (int q = 0; q < 4; ++q) vAE[q] = *(const float4*)(s + q * 4);
  };
  auto loadO = [&](int kt) {
    const float* s = pa + (size_t)(grE + 64) * DIM + kt * 64 + ac;
#pragma unroll
    for (int q = 0; q < 4; ++q) vAO[q] = *(const float4*)(s + q * 4);
  };
  auto packw = [&](float4 a, float4 b, unsigned short* dst) {
    uint4 o;
    o.x = (unsigned)f2bf(a.x) | ((unsigned)f2bf(a.y) << 16);
    o.y = (unsigned)f2bf(a.z) | ((unsigned)f2bf(a.w) << 16);
    o.z = (unsigned)f2bf(b.x) | ((unsigned)f2bf(b.y) << 16);
    o.w = (unsigned)f2bf(b.z) | ((unsigned)f2bf(b.w) << 16);
    *(uint4*)dst = o;
  };
  auto writeE = [&](int bufi) {
    int gr = grE, base = gr * 64, c8 = (tid & 3) * 2, xr = (gr & 7);
    packw(vAE[0], vAE[1], &As[bufi][base + ((c8 ^ xr) << 3)]);
    packw(vAE[2], vAE[3], &As[bufi][base + (((c8 + 1) ^ xr) << 3)]);
  };
  auto writeO = [&](int bufi) {
    int gr = grE + 64, base = gr * 64, c8 = (tid & 3) * 2, xr = (gr & 7);
    packw(vAO[0], vAO[1], &As[bufi][base + ((c8 ^ xr) << 3)]);
    packw(vAO[2], vAO[3], &As[bufi][base + (((c8 + 1) ^ xr) << 3)]);
  };
  auto stageB = [&](int kt, int h, int bufi) {
#pragma unroll
    for (int i = 0; i < 2; ++i) {
      int j0 = i * 64 + wid * 8;
      int rowbase = (j0 >> 5) * 64 + h * 32 + (j0 & 31);  // wave-uniform
      int row = rowbase + (lane >> 3);
      int scol = ((lane & 7) ^ (row & 7)) * 8;
      gload_lds16(pb + (size_t)row * DIM + kt * 64 + scol, &Bs[bufi][rowbase * 64]);
    }
  };

  // prologue: K-tile 0 -> buf 0
  loadE(0);            // 4 f4
  loadO(0);            // 4 f4
  stageB(0, 0, 0);     // 2 gld
  stageB(0, 1, 0);     // 2 gld
  writeE(0);           // reg-dep: vmcnt(8) (E landed)
  writeO(0);           // reg-dep: vmcnt(4) (O landed)
  asm volatile("s_waitcnt vmcnt(2)" ::: "memory");  // b0 landed (b1 in flight)
  asm volatile("s_waitcnt lgkmcnt(0)\n\ts_barrier" ::: "memory");

  for (int t = 0; t < 15; ++t) {
    const int ct = t & 1;
    // P1: reads A-E, B0 (resident); issue loadE(t+1) + stage b0'(t+1)
    READ_A(0); READ_B(0);
    loadE(t + 1);
    stageB(t + 1, 0, ct ^ 1);
    asm volatile("s_waitcnt vmcnt(6)\n\ts_barrier" ::: "memory");  // b1(t) landed
    MFMA_Q(0, 0);
    asm volatile("s_barrier" ::: "memory");
    // P2: reads B1; issue loadO(t+1) + stage b1'(t+1)
    READ_B(1);
    loadO(t + 1);
    stageB(t + 1, 1, ct ^ 1);
    asm volatile("s_barrier" ::: "memory");
    MFMA_Q(0, 1);
    asm volatile("s_barrier" ::: "memory");
    // P3: reads A-O; cvt+write E(t+1) (reg-dep waits loadE only)
    READ_A(1);
    writeE(ct ^ 1);
    asm volatile("s_waitcnt lgkmcnt(0)\n\ts_barrier" ::: "memory");
    MFMA_Q(1, 1);
    asm volatile("s_barrier" ::: "memory");
    // P4: cvt+write O(t+1) (reg-dep vmcnt retires b0', loadO)
    writeO(ct ^ 1);
    asm volatile("s_waitcnt lgkmcnt(0)\n\ts_barrier" ::: "memory");
    MFMA_Q(1, 0);
    asm volatile("s_barrier" ::: "memory");
  }
  {  // t = 15: no staging; drain b1 then compute
    const int ct = 1;
    READ_A(0); READ_B(0);
    asm volatile("s_waitcnt vmcnt(0)\n\ts_barrier" ::: "memory");
    MFMA_Q(0, 0);
    asm volatile("s_barrier" ::: "memory");
    READ_B(1);
    asm volatile("s_barrier" ::: "memory");
    MFMA_Q(0, 1);
    asm volatile("s_barrier" ::: "memory");
    READ_A(1);
    MFMA_Q(1, 1);
    MFMA_Q(1, 0);
  }

  // fused epilogue: psum over e, 16-lane shuffle reduce, atomic into att_l
  int b = m0 >> 9;
  const float* jrow = js + b * DIM;
  float jvv[4], vvv[4];
#pragma unroll
  for (int nj = 0; nj < 4; ++nj) {
    int e = n0 + wn * 64 + nj * 16 + lm;
    jvv[nj] = jrow[e] + w1bias[e];
    vvv[nj] = vw[e];
  }
#pragma unroll
  for (int mi = 0; mi < 8; ++mi) {
    float psum[4] = {0.f, 0.f, 0.f, 0.f};
#pragma unroll
    for (int nj = 0; nj < 4; ++nj)
#pragma unroll
      for (int r = 0; r < 4; ++r)
        psum[r] += tanh_fast(acc[mi][nj][r] + jvv[nj]) * vvv[nj];
#pragma unroll
    for (int r = 0; r < 4; ++r) {
      float s = psum[r];
      s += __shfl_xor(s, 1);
      s += __shfl_xor(s, 2);
      s += __shfl_xor(s, 4);
      s += __shfl_xor(s, 8);
      if (lm == 0)
        atomicAdd(&att_l[m0 + wm * 128 + mi * 16 + lq * 4 + r], s);
    }
  }
}
#undef READ_A
#undef READ_B
#undef MFMA_Q

// ---------------- softmax over s (512) per batch row -------------------------
__global__ void k_softmax(const float* __restrict__ att_l, float* __restrict__ att) {
  __shared__ float red[16];
  int b = blockIdx.x, t = threadIdx.x;  // 512 threads
  float v = att_l[b * SEQ + t];
  float m = v;
#pragma unroll
  for (int o = 32; o; o >>= 1) m = fmaxf(m, __shfl_xor(m, o));
  if ((t & 63) == 0) red[t >> 6] = m;
  __syncthreads();
  m = red[0];
#pragma unroll
  for (int i = 1; i < 8; ++i) m = fmaxf(m, red[i]);
  float e = __expf(v - m);
  float s = e;
#pragma unroll
  for (int o = 32; o; o >>= 1) s += __shfl_xor(s, o);
  __syncthreads();
  if ((t & 63) == 0) red[8 + (t >> 6)] = s;
  __syncthreads();
  s = 0.f;
#pragma unroll
  for (int i = 0; i < 8; ++i) s += red[8 + i];
  att[b * SEQ + t] = e / s;
}

// ---------------- LSTM pointwise + residual ----------------------------------
__global__ void k_lstm(const float* __restrict__ gates, const float* __restrict__ bih,
                       const float* __restrict__ bhh, const float* __restrict__ c,
                       const float* __restrict__ emb_f, float* __restrict__ out_h,
                       float* __restrict__ out_c, unsigned short* __restrict__ out_b) {
  int t = blockIdx.x * 256 + threadIdx.x;  // 65536
  int b = t >> 10, d = t & 1023;
  const float* g = gates + b * 4 * DIM;
  float ig = g[d] + bih[d] + bhh[d];
  float fg = g[DIM + d] + bih[DIM + d] + bhh[DIM + d];
  float gg = g[2 * DIM + d] + bih[2 * DIM + d] + bhh[2 * DIM + d];
  float og = g[3 * DIM + d] + bih[3 * DIM + d] + bhh[3 * DIM + d];
  float cn = sigmf(fg) * c[t] + sigmf(ig) * tanh_fast(gg);
  float hn = sigmf(og) * tanh_fast(cn);
  out_h[t] = hn;
  out_c[t] = cn;
  out_b[t] = f2bf(hn + emb_f[t]);  // residual, bf16 for logits GEMM
}

// -----------------------------------------------------------------------------
extern "C" void kernel_launch(void* const* d_in, const int* in_sizes, int n_in,
                              void* d_out, int out_size, void* d_ws, size_t ws_size,
                              hipStream_t stream) {
  const int* x = (const int*)d_in[0];
  const float* h = (const float*)d_in[1];
  const float* c = (const float*)d_in[2];
  const float* enc = (const float*)d_in[3];
  const float* Femb = (const float*)d_in[4];
  const float* W1w = (const float*)d_in[5];
  const float* W1b = (const float*)d_in[6];
  const float* W2w = (const float*)d_in[7];
  const float* W2b = (const float*)d_in[8];
  const float* Vw = (const float*)d_in[9];
  // d_in[10] = V_b: softmax-invariant, unused
  const float* Wih = (const float*)d_in[11];
  const float* Whh = (const float*)d_in[12];
  const float* bih = (const float*)d_in[13];
  const float* bhh = (const float*)d_in[14];
  const float* fcw = (const float*)d_in[15];
  const float* fcb = (const float*)d_in[16];

  float* out_logits = (float*)d_out;
  float* out_h = out_logits + (size_t)BATCH * VOCAB;
  float* out_c = out_h + BATCH * DIM;
  float* out_att = out_c + BATCH * DIM;

  char* p = (char*)d_ws;
  unsigned short* w1_b = (unsigned short*)p;  p += (size_t)DIM * DIM * 2;
  float* att_l = (float*)p;                   p += (size_t)M_SC * 4;
  float* js = (float*)p;                      p += (size_t)BATCH * DIM * 4;
  float* emb_f = (float*)p;                   p += (size_t)BATCH * DIM * 4;
  unsigned short* eh_b = (unsigned short*)p;  p += (size_t)BATCH * 2 * DIM * 2;
  unsigned short* h_b = (unsigned short*)p;   p += (size_t)BATCH * DIM * 2;
  float* gates = (float*)p;                   p += (size_t)BATCH * 4 * DIM * 4;
  unsigned short* out_b = (unsigned short*)p; p += (size_t)BATCH * DIM * 2;

  hipLaunchKernelGGL(k_small, dim3(1024), dim3(256), 0, stream,
                     W1w, w1_b, att_l, x, Femb, h, emb_f, eh_b, h_b);
  // j_s = h @ W2^T + W2_b  -> [64][1024]
  hipLaunchKernelGGL(k_skinny, dim3(DIM / 16), dim3(256), 0, stream,
                     h_b, DIM, W2w, W2w, DIM, W2b, js, DIM, DIM);
  // fused attention scores (reads enc fp32 directly; 8-phase 256x256)
  hipLaunchKernelGGL(k_score, dim3(512), dim3(512), 0, stream,
                     enc, w1_b, js, W1b, Vw, att_l);
  hipLaunchKernelGGL(k_softmax, dim3(BATCH), dim3(SEQ), 0, stream, att_l, out_att);
  // gates = [emb|h] @ [W_ih|W_hh]^T  -> [64][4096] (biases added in k_lstm)
  hipLaunchKernelGGL(k_skinny, dim3(4 * DIM / 16), dim3(256), 0, stream,
                     eh_b, 2 * DIM, Wih, Whh, DIM, (const float*)nullptr, gates, 4 * DIM, 2 * DIM);
  hipLaunchKernelGGL(k_lstm, dim3(BATCH * DIM / 256), dim3(256), 0, stream,
                     gates, bih, bhh, c, emb_f, out_h, out_c, out_b);
  // logits = (h_new + emb) @ fc_w^T + fc_b  (N-tile 32)
  hipLaunchKernelGGL(k_skinny32, dim3(VOCAB / 32), dim3(256), 0, stream,
                     out_b, fcw, fcb, out_logits, VOCAB, DIM);
}

// Round 11
// 179.551 us; speedup vs baseline: 1.2296x; 1.2296x over previous
//
#include <hip/hip_runtime.h>

#define DEV __device__ __forceinline__

typedef __bf16 bf16_t;
typedef bf16_t bf16x8 __attribute__((ext_vector_type(8)));
typedef float f32x4 __attribute__((ext_vector_type(4)));

static constexpr int VOCAB = 32000, DIM = 1024, BATCH = 64, SEQ = 512;
static constexpr int M_SC = BATCH * SEQ;  // 32768

DEV unsigned short f2bf(float f) {
  unsigned u = __builtin_bit_cast(unsigned, f);
  u += 0x7FFFu + ((u >> 16) & 1u);  // RNE, inputs are finite
  return (unsigned short)(u >> 16);
}

DEV float sigmf(float x) {
  x = fminf(fmaxf(x, -30.f), 30.f);
  return 1.0f / (1.0f + __expf(-x));
}

DEV float tanh_fast(float x) {
  x = fminf(fmaxf(x, -20.f), 20.f);
  float e = __expf(2.0f * x);
  return (e - 1.0f) / (e + 1.0f);
}

DEV void gload_lds16(const void* g, void* l) {
  __builtin_amdgcn_global_load_lds(
      (__attribute__((address_space(1))) void*)(g),
      (__attribute__((address_space(3))) void*)(l), 16, 0, 0);
}

// ---------------- prep: enc_y + W1 -> bf16, zero att, embed gather ----------
__global__ void __launch_bounds__(256) k_prep(const float* __restrict__ enc,
                                              const float* __restrict__ w1,
                                              unsigned short* __restrict__ enc_b,
                                              unsigned short* __restrict__ w1_b,
                                              float* __restrict__ att_l,
                                              const int* __restrict__ x,
                                              const float* __restrict__ Femb,
                                              const float* __restrict__ h,
                                              float* __restrict__ emb_f,
                                              unsigned short* __restrict__ eh_b,
                                              unsigned short* __restrict__ h_b) {
  // last 64 blocks also do the embedding gather (tiny, hides in the stream)
  if (blockIdx.x >= 1984) {
    int b = blockIdx.x - 1984;
    int tok = x[b];
    for (int d = threadIdx.x; d < DIM; d += 256) {
      float e = Femb[(size_t)tok * DIM + d];
      float hv = h[b * DIM + d];
      emb_f[b * DIM + d] = e;
      unsigned short eb = f2bf(e), hb = f2bf(hv);
      eh_b[b * 2 * DIM + d] = eb;
      eh_b[b * 2 * DIM + DIM + d] = hb;
      h_b[b * DIM + d] = hb;
    }
  }
  int gid = blockIdx.x * 256 + threadIdx.x;
  if (gid < M_SC) att_l[gid] = 0.f;
  const int ENC4 = (M_SC * DIM) / 4;       // 8388608
  const int TOT4 = ENC4 + (DIM * DIM) / 4; // + 262144
  int stride = gridDim.x * 256;
  for (int i = gid; i < TOT4; i += stride) {
    float4 v;
    unsigned short* dst;
    if (i < ENC4) {
      v = ((const float4*)enc)[i];
      dst = enc_b + (size_t)i * 4;
    } else {
      v = ((const float4*)w1)[i - ENC4];
      dst = w1_b + (size_t)(i - ENC4) * 4;
    }
    ushort4 o;
    o.x = f2bf(v.x); o.y = f2bf(v.y); o.z = f2bf(v.z); o.w = f2bf(v.w);
    *(ushort4*)dst = o;
  }
}

// ---------------- skinny GEMM: C[64 x N] = A(bf16) . W(f32,[*][1024])^T -----
// N-tile 16/block, K-tile 128, 4 waves. Counted-vmcnt double buffer (R4,
// verified). LDS XOR swizzle throughout.
__global__ void __launch_bounds__(256) k_skinny(
    const unsigned short* __restrict__ A, int lda,
    const float* __restrict__ B1, const float* __restrict__ B2, int ksplit,
    const float* __restrict__ bias, float* __restrict__ C, int N, int K) {
  __shared__ unsigned short As[2][64 * 128];
  __shared__ unsigned short Bs[2][16 * 128];
  int t = threadIdx.x;
  int l = t & 63, w = t >> 6;
  int n0 = blockIdx.x * 16;
  f32x4 acc = {};
  int rx = (l & 7) << 3;  // read-side XOR (elems)

  float4 vB[2];

  auto loadB = [&](int k0) {
    const float* Bsrc;
    int kk;
    if (k0 < ksplit) { Bsrc = B1; kk = k0; } else { Bsrc = B2; kk = k0 - ksplit; }
#pragma unroll
    for (int i = 0; i < 2; ++i) {
      int lin = i * 256 + t;
      int row = lin >> 5, c4 = (lin & 31) * 4;
      vB[i] = *(const float4*)(Bsrc + (size_t)(n0 + row) * 1024 + kk + c4);
    }
  };
  auto writeB = [&](int bufi) {
#pragma unroll
    for (int i = 0; i < 2; ++i) {
      int lin = i * 256 + t;
      int row = lin >> 5, c4 = (lin & 31) * 4;
      ushort4 o;
      o.x = f2bf(vB[i].x); o.y = f2bf(vB[i].y); o.z = f2bf(vB[i].z); o.w = f2bf(vB[i].w);
      *(ushort4*)&Bs[bufi][row * 128 + (c4 ^ ((row & 7) << 3))] = o;
    }
  };
  auto stageA = [&](int k0, int bufi) {
#pragma unroll
    for (int i = 0; i < 4; ++i) {
      int sbase = i * 256 + w * 64;       // wave-uniform 16B-slot base
      int s = sbase + l;
      int row = s >> 4;                   // 16 slots per 128-elem row
      int scol = ((s & 15) ^ (row & 7)) * 8;
      gload_lds16(A + (size_t)row * lda + k0 + scol, &As[bufi][sbase * 8]);
    }
  };
  auto compute = [&](int bufi) {
#pragma unroll
    for (int kf = 0; kf < 4; ++kf) {
      int ko = kf * 32 + 8 * (l >> 4);
      int ar = w * 16 + (l & 15);
      bf16x8 af = *(const bf16x8*)&As[bufi][ar * 128 + (ko ^ rx)];
      bf16x8 bf = *(const bf16x8*)&Bs[bufi][(l & 15) * 128 + (ko ^ rx)];
      acc = __builtin_amdgcn_mfma_f32_16x16x32_bf16(af, bf, acc, 0, 0, 0);
    }
  };

  loadB(0);
  stageA(0, 0);
  writeB(0);
  asm volatile("s_waitcnt lgkmcnt(0)" ::: "memory");

  int nk = K / 128;
  int cur = 0;
  for (int kt = 0; kt < nk - 1; ++kt) {
    loadB((kt + 1) * 128);             // 2 global->reg, in flight
    stageA((kt + 1) * 128, cur ^ 1);   // 4 global->LDS, in flight
    asm volatile("s_waitcnt vmcnt(6)\n\ts_barrier" ::: "memory");
    compute(cur);
    writeB(cur ^ 1);                   // compiler waits vB regs only
    asm volatile("s_waitcnt lgkmcnt(0)\n\ts_barrier" ::: "memory");
    cur ^= 1;
  }
  asm volatile("s_waitcnt vmcnt(0)\n\ts_barrier" ::: "memory");
  compute(cur);

  int cn = n0 + (l & 15);
  float bv = bias ? bias[cn] : 0.f;
#pragma unroll
  for (int r = 0; r < 4; ++r) {
    int m = w * 16 + (l >> 4) * 4 + r;
    C[(size_t)m * N + cn] = acc[r] + bv;
  }
}

// ---------------- skinny GEMM, N-tile 32 (for logits) -----------------------
__global__ void __launch_bounds__(256) k_skinny32(
    const unsigned short* __restrict__ A,
    const float* __restrict__ B, const float* __restrict__ bias,
    float* __restrict__ C, int N, int K) {
  __shared__ unsigned short As[2][64 * 128];
  __shared__ unsigned short Bs[2][32 * 128];
  int t = threadIdx.x;
  int l = t & 63, w = t >> 6;
  int n0 = blockIdx.x * 32;
  f32x4 acc0 = {}, acc1 = {};
  int rx = (l & 7) << 3;

  float4 vB[4];

  auto loadB = [&](int k0) {
#pragma unroll
    for (int i = 0; i < 4; ++i) {
      int lin = i * 256 + t;
      int row = lin >> 5, c4 = (lin & 31) * 4;
      vB[i] = *(const float4*)(B + (size_t)(n0 + row) * 1024 + k0 + c4);
    }
  };
  auto writeB = [&](int bufi) {
#pragma unroll
    for (int i = 0; i < 4; ++i) {
      int lin = i * 256 + t;
      int row = lin >> 5, c4 = (lin & 31) * 4;
      ushort4 o;
      o.x = f2bf(vB[i].x); o.y = f2bf(vB[i].y); o.z = f2bf(vB[i].z); o.w = f2bf(vB[i].w);
      *(ushort4*)&Bs[bufi][row * 128 + (c4 ^ ((row & 7) << 3))] = o;
    }
  };
  auto stageA = [&](int k0, int bufi) {
#pragma unroll
    for (int i = 0; i < 4; ++i) {
      int sbase = i * 256 + w * 64;
      int s = sbase + l;
      int row = s >> 4;
      int scol = ((s & 15) ^ (row & 7)) * 8;
      gload_lds16(A + (size_t)row * DIM + k0 + scol, &As[bufi][sbase * 8]);
    }
  };
  auto compute = [&](int bufi) {
#pragma unroll
    for (int kf = 0; kf < 4; ++kf) {
      int ko = kf * 32 + 8 * (l >> 4);
      int ar = w * 16 + (l & 15);
      bf16x8 af = *(const bf16x8*)&As[bufi][ar * 128 + (ko ^ rx)];
      bf16x8 b0 = *(const bf16x8*)&Bs[bufi][(l & 15) * 128 + (ko ^ rx)];
      bf16x8 b1 = *(const bf16x8*)&Bs[bufi][((l & 15) + 16) * 128 + (ko ^ rx)];
      acc0 = __builtin_amdgcn_mfma_f32_16x16x32_bf16(af, b0, acc0, 0, 0, 0);
      acc1 = __builtin_amdgcn_mfma_f32_16x16x32_bf16(af, b1, acc1, 0, 0, 0);
    }
  };

  loadB(0);
  stageA(0, 0);
  writeB(0);
  asm volatile("s_waitcnt lgkmcnt(0)" ::: "memory");

  int nk = K / 128;
  int cur = 0;
  for (int kt = 0; kt < nk - 1; ++kt) {
    loadB((kt + 1) * 128);
    stageA((kt + 1) * 128, cur ^ 1);
    asm volatile("s_waitcnt vmcnt(8)\n\ts_barrier" ::: "memory");
    compute(cur);
    writeB(cur ^ 1);
    asm volatile("s_waitcnt lgkmcnt(0)\n\ts_barrier" ::: "memory");
    cur ^= 1;
  }
  asm volatile("s_waitcnt vmcnt(0)\n\ts_barrier" ::: "memory");
  compute(cur);

  int cn = n0 + (l & 15);
  float bv0 = bias ? bias[cn] : 0.f;
  float bv1 = bias ? bias[cn + 16] : 0.f;
#pragma unroll
  for (int r = 0; r < 4; ++r) {
    int m = w * 16 + (l >> 4) * 4 + r;
    C[(size_t)m * N + cn] = acc0[r] + bv0;
    C[(size_t)m * N + cn + 16] = acc1[r] + bv1;
  }
}

// ---------------- big fused score GEMM: 8-phase 256x256 (R6/R8, verified) ----
#define READ_A(MH)                                                              \
  do {                                                                          \
    _Pragma("unroll") for (int mf = 0; mf < 4; ++mf)                            \
    _Pragma("unroll") for (int kk = 0; kk < 2; ++kk) {                          \
      int row_ = wm * 128 + (MH) * 64 + mf * 16 + lm;                           \
      fa[mf][kk] = *(const bf16x8*)&As[ct][row_ * 64 + ((kk * 32 + 8 * lq) ^ rx)]; \
    }                                                                           \
  } while (0)
#define READ_B(NH)                                                              \
  do {                                                                          \
    _Pragma("unroll") for (int nf = 0; nf < 2; ++nf)                            \
    _Pragma("unroll") for (int kk = 0; kk < 2; ++kk) {                          \
      int row_ = wn * 64 + (NH) * 32 + nf * 16 + lm;                            \
      fb[NH][nf][kk] = *(const bf16x8*)&Bs[ct][row_ * 64 + ((kk * 32 + 8 * lq) ^ rx)]; \
    }                                                                           \
  } while (0)
#define MFMA_Q(MH, NH)                                                          \
  do {                                                                          \
    __builtin_amdgcn_s_setprio(1);                                              \
    _Pragma("unroll") for (int mf = 0; mf < 4; ++mf)                            \
    _Pragma("unroll") for (int nf = 0; nf < 2; ++nf)                            \
    _Pragma("unroll") for (int kk = 0; kk < 2; ++kk)                            \
        acc[(MH) * 4 + mf][(NH) * 2 + nf] = __builtin_amdgcn_mfma_f32_16x16x32_bf16( \
            fa[mf][kk], fb[NH][nf][kk], acc[(MH) * 4 + mf][(NH) * 2 + nf], 0, 0, 0); \
    __builtin_amdgcn_s_setprio(0);                                              \
  } while (0)

__global__ void __launch_bounds__(512, 2) k_score(
    const unsigned short* __restrict__ encb, const unsigned short* __restrict__ w1mat,
    const float* __restrict__ js, const float* __restrict__ w1bias,
    const float* __restrict__ vw, float* __restrict__ att_l) {
  __shared__ unsigned short As[2][256 * 64];  // 2 x 32 KB
  __shared__ unsigned short Bs[2][256 * 64];  // 2 x 32 KB
  int tid = threadIdx.x;
  int lane = tid & 63, wid = tid >> 6;
  int wm = wid >> 2, wn = wid & 3;   // 2 x 4 wave grid
  int lm = lane & 15, lq = lane >> 4;
  int rx = (lane & 7) << 3;          // read-side XOR (elems)

  int wg = blockIdx.x;               // 512 blocks (%8==0, bijective)
  int swz = (wg & 7) * 64 + (wg >> 3);
  int m0 = (swz >> 2) * 256;         // XCD i owns m-tiles [i*16,(i+1)*16)
  int n0 = (swz & 3) * 256;          // n fastest -> A-tiles L2-shared in XCD

  const unsigned short* pa = encb + (size_t)m0 * DIM;
  const unsigned short* pb = w1mat + (size_t)n0 * DIM;

  f32x4 acc[8][4] = {};
  bf16x8 fa[4][2];       // current A half (mh), [mf][kk]
  bf16x8 fb[2][2][2];    // both B halves,   [nh][nf][kk]

  auto stageA = [&](int kt, int h, int bufi) {
#pragma unroll
    for (int i = 0; i < 2; ++i) {
      int rowbase = i * 128 + h * 64 + wid * 8;   // wave-uniform
      int row = rowbase + (lane >> 3);
      int scol = ((lane & 7) ^ (row & 7)) * 8;
      gload_lds16(pa + (size_t)row * DIM + kt * 64 + scol, &As[bufi][rowbase * 64]);
    }
  };
  auto stageB = [&](int kt, int h, int bufi) {
#pragma unroll
    for (int i = 0; i < 2; ++i) {
      int j0 = i * 64 + wid * 8;
      int rowbase = (j0 >> 5) * 64 + h * 32 + (j0 & 31);  // wave-uniform
      int row = rowbase + (lane >> 3);
      int scol = ((lane & 7) ^ (row & 7)) * 8;
      gload_lds16(pb + (size_t)row * DIM + kt * 64 + scol, &Bs[bufi][rowbase * 64]);
    }
  };

  // prologue: K-tile 0 -> buf 0, in consumption order a0,b0,b1,a1 (8 loads)
  stageA(0, 0, 0);
  stageB(0, 0, 0);
  stageB(0, 1, 0);
  stageA(0, 1, 0);
  asm volatile("s_waitcnt vmcnt(4)\n\ts_barrier" ::: "memory");  // a0,b0 landed

  for (int t = 0; t < 15; ++t) {
    const int ct = t & 1;
    // P1: reads A0,B0 (covered by prev P4 wait); stage a0'(t+1)
    READ_A(0); READ_B(0);
    stageA(t + 1, 0, ct ^ 1);
    asm volatile("s_waitcnt vmcnt(4)\n\ts_barrier" ::: "memory");  // b1(t) landed
    MFMA_Q(0, 0);
    asm volatile("s_barrier" ::: "memory");
    // P2: reads B1; stage b0'(t+1)
    READ_B(1);
    stageB(t + 1, 0, ct ^ 1);
    asm volatile("s_waitcnt vmcnt(4)\n\ts_barrier" ::: "memory");  // a1(t) landed
    MFMA_Q(0, 1);
    asm volatile("s_barrier" ::: "memory");
    // P3: reads A1; stage b1'(t+1); no vmcnt (P4 reads nothing)
    READ_A(1);
    stageB(t + 1, 1, ct ^ 1);
    asm volatile("s_barrier" ::: "memory");
    MFMA_Q(1, 1);
    asm volatile("s_barrier" ::: "memory");
    // P4: stage a1'(t+1)
    stageA(t + 1, 1, ct ^ 1);
    asm volatile("s_waitcnt vmcnt(4)\n\ts_barrier" ::: "memory");  // a0',b0' landed
    MFMA_Q(1, 0);
    asm volatile("s_barrier" ::: "memory");
  }
  {  // t = 15, no staging; drain 4 -> 2 -> 0
    const int ct = 1;
    READ_A(0); READ_B(0);
    asm volatile("s_waitcnt vmcnt(2)\n\ts_barrier" ::: "memory");  // b1 landed
    MFMA_Q(0, 0);
    asm volatile("s_barrier" ::: "memory");
    READ_B(1);
    asm volatile("s_waitcnt vmcnt(0)\n\ts_barrier" ::: "memory");  // a1 landed
    MFMA_Q(0, 1);
    asm volatile("s_barrier" ::: "memory");
    READ_A(1);
    MFMA_Q(1, 1);
    MFMA_Q(1, 0);
  }

  // fused epilogue: psum over e, 16-lane shuffle reduce, atomic into att_l
  int b = m0 >> 9;  // 256-row tile lies within one batch block (512 rows)
  const float* jrow = js + b * DIM;
  float jvv[4], vvv[4];
#pragma unroll
  for (int nj = 0; nj < 4; ++nj) {
    int e = n0 + wn * 64 + nj * 16 + lm;
    jvv[nj] = jrow[e] + w1bias[e];
    vvv[nj] = vw[e];
  }
#pragma unroll
  for (int mi = 0; mi < 8; ++mi) {
    float psum[4] = {0.f, 0.f, 0.f, 0.f};
#pragma unroll
    for (int nj = 0; nj < 4; ++nj)
#pragma unroll
      for (int r = 0; r < 4; ++r)
        psum[r] += tanh_fast(acc[mi][nj][r] + jvv[nj]) * vvv[nj];
#pragma unroll
    for (int r = 0; r < 4; ++r) {
      float s = psum[r];
      s += __shfl_xor(s, 1);
      s += __shfl_xor(s, 2);
      s += __shfl_xor(s, 4);
      s += __shfl_xor(s, 8);
      if (lm == 0)
        atomicAdd(&att_l[m0 + wm * 128 + mi * 16 + lq * 4 + r], s);
    }
  }
}
#undef READ_A
#undef READ_B
#undef MFMA_Q

// ---------------- LSTM pointwise + residual, + softmax (blocks 256-319) ------
__global__ void __launch_bounds__(256) k_lstm(
    const float* __restrict__ gates, const float* __restrict__ bih,
    const float* __restrict__ bhh, const float* __restrict__ c,
    const float* __restrict__ emb_f, float* __restrict__ out_h,
    float* __restrict__ out_c, unsigned short* __restrict__ out_b,
    const float* __restrict__ att_l, float* __restrict__ att) {
  if (blockIdx.x >= 256) {  // softmax over s (512) for batch row b, 256 threads
    __shared__ float red[8];
    int b = blockIdx.x - 256;
    int t = threadIdx.x;
    float v0 = att_l[b * SEQ + t];
    float v1 = att_l[b * SEQ + t + 256];
    float m = fmaxf(v0, v1);
#pragma unroll
    for (int o = 32; o; o >>= 1) m = fmaxf(m, __shfl_xor(m, o));
    if ((t & 63) == 0) red[t >> 6] = m;
    __syncthreads();
    m = fmaxf(fmaxf(red[0], red[1]), fmaxf(red[2], red[3]));
    float e0 = __expf(v0 - m), e1 = __expf(v1 - m);
    float s = e0 + e1;
#pragma unroll
    for (int o = 32; o; o >>= 1) s += __shfl_xor(s, o);
    __syncthreads();
    if ((t & 63) == 0) red[4 + (t >> 6)] = s;
    __syncthreads();
    s = red[4] + red[5] + red[6] + red[7];
    att[b * SEQ + t] = e0 / s;
    att[b * SEQ + t + 256] = e1 / s;
    return;
  }
  int t = blockIdx.x * 256 + threadIdx.x;  // 65536
  int b = t >> 10, d = t & 1023;
  const float* g = gates + b * 4 * DIM;
  float ig = g[d] + bih[d] + bhh[d];
  float fg = g[DIM + d] + bih[DIM + d] + bhh[DIM + d];
  float gg = g[2 * DIM + d] + bih[2 * DIM + d] + bhh[2 * DIM + d];
  float og = g[3 * DIM + d] + bih[3 * DIM + d] + bhh[3 * DIM + d];
  float cn = sigmf(fg) * c[t] + sigmf(ig) * tanh_fast(gg);
  float hn = sigmf(og) * tanh_fast(cn);
  out_h[t] = hn;
  out_c[t] = cn;
  out_b[t] = f2bf(hn + emb_f[t]);  // residual, bf16 for logits GEMM
}

// -----------------------------------------------------------------------------
extern "C" void kernel_launch(void* const* d_in, const int* in_sizes, int n_in,
                              void* d_out, int out_size, void* d_ws, size_t ws_size,
                              hipStream_t stream) {
  const int* x = (const int*)d_in[0];
  const float* h = (const float*)d_in[1];
  const float* c = (const float*)d_in[2];
  const float* enc = (const float*)d_in[3];
  const float* Femb = (const float*)d_in[4];
  const float* W1w = (const float*)d_in[5];
  const float* W1b = (const float*)d_in[6];
  const float* W2w = (const float*)d_in[7];
  const float* W2b = (const float*)d_in[8];
  const float* Vw = (const float*)d_in[9];
  // d_in[10] = V_b: softmax-invariant, unused
  const float* Wih = (const float*)d_in[11];
  const float* Whh = (const float*)d_in[12];
  const float* bih = (const float*)d_in[13];
  const float* bhh = (const float*)d_in[14];
  const float* fcw = (const float*)d_in[15];
  const float* fcb = (const float*)d_in[16];

  float* out_logits = (float*)d_out;
  float* out_h = out_logits + (size_t)BATCH * VOCAB;
  float* out_c = out_h + BATCH * DIM;
  float* out_att = out_c + BATCH * DIM;

  char* p = (char*)d_ws;
  unsigned short* enc_b = (unsigned short*)p; p += (size_t)M_SC * DIM * 2;
  unsigned short* w1_b = (unsigned short*)p;  p += (size_t)DIM * DIM * 2;
  float* att_l = (float*)p;                   p += (size_t)M_SC * 4;
  float* js = (float*)p;                      p += (size_t)BATCH * DIM * 4;
  float* emb_f = (float*)p;                   p += (size_t)BATCH * DIM * 4;
  unsigned short* eh_b = (unsigned short*)p;  p += (size_t)BATCH * 2 * DIM * 2;
  unsigned short* h_b = (unsigned short*)p;   p += (size_t)BATCH * DIM * 2;
  float* gates = (float*)p;                   p += (size_t)BATCH * 4 * DIM * 4;
  unsigned short* out_b = (unsigned short*)p; p += (size_t)BATCH * DIM * 2;

  hipLaunchKernelGGL(k_prep, dim3(2048), dim3(256), 0, stream, enc, W1w, enc_b, w1_b,
                     att_l, x, Femb, h, emb_f, eh_b, h_b);
  // j_s = h @ W2^T + W2_b  -> [64][1024]
  hipLaunchKernelGGL(k_skinny, dim3(DIM / 16), dim3(256), 0, stream,
                     h_b, DIM, W2w, W2w, DIM, W2b, js, DIM, DIM);
  // fused attention scores -> att_l (8-phase 256x256)
  hipLaunchKernelGGL(k_score, dim3(512), dim3(512), 0, stream,
                     enc_b, w1_b, js, W1b, Vw, att_l);
  // gates = [emb|h] @ [W_ih|W_hh]^T  -> [64][4096] (biases added in k_lstm)
  hipLaunchKernelGGL(k_skinny, dim3(4 * DIM / 16), dim3(256), 0, stream,
                     eh_b, 2 * DIM, Wih, Whh, DIM, (const float*)nullptr, gates, 4 * DIM, 2 * DIM);
  // lstm pointwise (blocks 0-255) + softmax (blocks 256-319)
  hipLaunchKernelGGL(k_lstm, dim3(320), dim3(256), 0, stream,
                     gates, bih, bhh, c, emb_f, out_h, out_c, out_b, att_l, out_att);
  // logits = (h_new + emb) @ fc_w^T + fc_b  (N-tile 32)
  hipLaunchKernelGGL(k_skinny32, dim3(VOCAB / 32), dim3(256), 0, stream,
                     out_b, fcw, fcb, out_logits, VOCAB, DIM);
}

// Round 12
// 169.340 us; speedup vs baseline: 1.3037x; 1.0603x over previous
//
#include <hip/hip_runtime.h>

#define DEV __device__ __forceinline__

typedef __bf16 bf16_t;
typedef bf16_t bf16x8 __attribute__((ext_vector_type(8)));
typedef float f32x4 __attribute__((ext_vector_type(4)));

static constexpr int VOCAB = 32000, DIM = 1024, BATCH = 64, SEQ = 512;
static constexpr int M_SC = BATCH * SEQ;  // 32768

DEV unsigned short f2bf(float f) {
  unsigned u = __builtin_bit_cast(unsigned, f);
  u += 0x7FFFu + ((u >> 16) & 1u);  // RNE, inputs are finite
  return (unsigned short)(u >> 16);
}

DEV float sigmf(float x) {
  x = fminf(fmaxf(x, -30.f), 30.f);
  return 1.0f / (1.0f + __expf(-x));
}

DEV float tanh_fast(float x) {
  x = fminf(fmaxf(x, -20.f), 20.f);
  float e = __expf(2.0f * x);
  return (e - 1.0f) / (e + 1.0f);
}

DEV void gload_lds16(const void* g, void* l) {
  __builtin_amdgcn_global_load_lds(
      (__attribute__((address_space(1))) void*)(g),
      (__attribute__((address_space(3))) void*)(l), 16, 0, 0);
}

// ---------------- prep: enc_y + W1 -> bf16, zero att, embed gather ----------
__global__ void __launch_bounds__(256) k_prep(const float* __restrict__ enc,
                                              const float* __restrict__ w1,
                                              unsigned short* __restrict__ enc_b,
                                              unsigned short* __restrict__ w1_b,
                                              float* __restrict__ att_l,
                                              const int* __restrict__ x,
                                              const float* __restrict__ Femb,
                                              const float* __restrict__ h,
                                              float* __restrict__ emb_f,
                                              unsigned short* __restrict__ eh_b,
                                              unsigned short* __restrict__ h_b) {
  // last 64 blocks also do the embedding gather (tiny, hides in the stream)
  if (blockIdx.x >= 1984) {
    int b = blockIdx.x - 1984;
    int tok = x[b];
    for (int d = threadIdx.x; d < DIM; d += 256) {
      float e = Femb[(size_t)tok * DIM + d];
      float hv = h[b * DIM + d];
      emb_f[b * DIM + d] = e;
      unsigned short eb = f2bf(e), hb = f2bf(hv);
      eh_b[b * 2 * DIM + d] = eb;
      eh_b[b * 2 * DIM + DIM + d] = hb;
      h_b[b * DIM + d] = hb;
    }
  }
  int gid = blockIdx.x * 256 + threadIdx.x;
  if (gid < M_SC) att_l[gid] = 0.f;
  const int ENC4 = (M_SC * DIM) / 4;       // 8388608
  const int TOT4 = ENC4 + (DIM * DIM) / 4; // + 262144
  int stride = gridDim.x * 256;
  for (int i = gid; i < TOT4; i += stride) {
    float4 v;
    unsigned short* dst;
    if (i < ENC4) {
      v = ((const float4*)enc)[i];
      dst = enc_b + (size_t)i * 4;
    } else {
      v = ((const float4*)w1)[i - ENC4];
      dst = w1_b + (size_t)(i - ENC4) * 4;
    }
    ushort4 o;
    o.x = f2bf(v.x); o.y = f2bf(v.y); o.z = f2bf(v.z); o.w = f2bf(v.w);
    *(ushort4*)dst = o;
  }
}

// ---------------- dual skinny GEMM: two configs in one launch ---------------
// Blocks [0, nb1): config 1 (gates); blocks [nb1, ...): config 2 (js).
// Per-block uniform config -> barriers/loop trip counts uniform within block.
// C[64 x N] = A(bf16) . W(f32,[*][1024])^T; counted-vmcnt double buffer (R4,
// verified), LDS XOR swizzle.
__global__ void __launch_bounds__(256) k_skinny(
    const unsigned short* __restrict__ A1p, int lda1,
    const float* __restrict__ B1a, const float* __restrict__ B1b, int ksplit1,
    const float* __restrict__ bias1, float* __restrict__ C1, int N1, int K1,
    int nb1,
    const unsigned short* __restrict__ A2p, int lda2,
    const float* __restrict__ B2a, const float* __restrict__ B2b, int ksplit2,
    const float* __restrict__ bias2, float* __restrict__ C2, int N2, int K2) {
  __shared__ unsigned short As[2][64 * 128];
  __shared__ unsigned short Bs[2][16 * 128];
  int t = threadIdx.x;
  int l = t & 63, w = t >> 6;

  const unsigned short* A;
  const float *B1, *B2, *bias;
  float* C;
  int lda, ksplit, N, K, n0;
  if ((int)blockIdx.x < nb1) {
    A = A1p; lda = lda1; B1 = B1a; B2 = B1b; ksplit = ksplit1;
    bias = bias1; C = C1; N = N1; K = K1; n0 = blockIdx.x * 16;
  } else {
    A = A2p; lda = lda2; B1 = B2a; B2 = B2b; ksplit = ksplit2;
    bias = bias2; C = C2; N = N2; K = K2; n0 = (blockIdx.x - nb1) * 16;
  }

  f32x4 acc = {};
  int rx = (l & 7) << 3;  // read-side XOR (elems)

  float4 vB[2];

  auto loadB = [&](int k0) {
    const float* Bsrc;
    int kk;
    if (k0 < ksplit) { Bsrc = B1; kk = k0; } else { Bsrc = B2; kk = k0 - ksplit; }
#pragma unroll
    for (int i = 0; i < 2; ++i) {
      int lin = i * 256 + t;
      int row = lin >> 5, c4 = (lin & 31) * 4;
      vB[i] = *(const float4*)(Bsrc + (size_t)(n0 + row) * 1024 + kk + c4);
    }
  };
  auto writeB = [&](int bufi) {
#pragma unroll
    for (int i = 0; i < 2; ++i) {
      int lin = i * 256 + t;
      int row = lin >> 5, c4 = (lin & 31) * 4;
      ushort4 o;
      o.x = f2bf(vB[i].x); o.y = f2bf(vB[i].y); o.z = f2bf(vB[i].z); o.w = f2bf(vB[i].w);
      *(ushort4*)&Bs[bufi][row * 128 + (c4 ^ ((row & 7) << 3))] = o;
    }
  };
  auto stageA = [&](int k0, int bufi) {
#pragma unroll
    for (int i = 0; i < 4; ++i) {
      int sbase = i * 256 + w * 64;       // wave-uniform 16B-slot base
      int s = sbase + l;
      int row = s >> 4;                   // 16 slots per 128-elem row
      int scol = ((s & 15) ^ (row & 7)) * 8;
      gload_lds16(A + (size_t)row * lda + k0 + scol, &As[bufi][sbase * 8]);
    }
  };
  auto compute = [&](int bufi) {
#pragma unroll
    for (int kf = 0; kf < 4; ++kf) {
      int ko = kf * 32 + 8 * (l >> 4);
      int ar = w * 16 + (l & 15);
      bf16x8 af = *(const bf16x8*)&As[bufi][ar * 128 + (ko ^ rx)];
      bf16x8 bf = *(const bf16x8*)&Bs[bufi][(l & 15) * 128 + (ko ^ rx)];
      acc = __builtin_amdgcn_mfma_f32_16x16x32_bf16(af, bf, acc, 0, 0, 0);
    }
  };

  loadB(0);
  stageA(0, 0);
  writeB(0);
  asm volatile("s_waitcnt lgkmcnt(0)" ::: "memory");

  int nk = K / 128;
  int cur = 0;
  for (int kt = 0; kt < nk - 1; ++kt) {
    loadB((kt + 1) * 128);             // 2 global->reg, in flight
    stageA((kt + 1) * 128, cur ^ 1);   // 4 global->LDS, in flight
    asm volatile("s_waitcnt vmcnt(6)\n\ts_barrier" ::: "memory");
    compute(cur);
    writeB(cur ^ 1);                   // compiler waits vB regs only
    asm volatile("s_waitcnt lgkmcnt(0)\n\ts_barrier" ::: "memory");
    cur ^= 1;
  }
  asm volatile("s_waitcnt vmcnt(0)\n\ts_barrier" ::: "memory");
  compute(cur);

  int cn = n0 + (l & 15);
  float bv = bias ? bias[cn] : 0.f;
#pragma unroll
  for (int r = 0; r < 4; ++r) {
    int m = w * 16 + (l >> 4) * 4 + r;
    C[(size_t)m * N + cn] = acc[r] + bv;
  }
}

// ---------------- skinny GEMM, N-tile 32 (for logits) -----------------------
__global__ void __launch_bounds__(256) k_skinny32(
    const unsigned short* __restrict__ A,
    const float* __restrict__ B, const float* __restrict__ bias,
    float* __restrict__ C, int N, int K) {
  __shared__ unsigned short As[2][64 * 128];
  __shared__ unsigned short Bs[2][32 * 128];
  int t = threadIdx.x;
  int l = t & 63, w = t >> 6;
  int n0 = blockIdx.x * 32;
  f32x4 acc0 = {}, acc1 = {};
  int rx = (l & 7) << 3;

  float4 vB[4];

  auto loadB = [&](int k0) {
#pragma unroll
    for (int i = 0; i < 4; ++i) {
      int lin = i * 256 + t;
      int row = lin >> 5, c4 = (lin & 31) * 4;
      vB[i] = *(const float4*)(B + (size_t)(n0 + row) * 1024 + k0 + c4);
    }
  };
  auto writeB = [&](int bufi) {
#pragma unroll
    for (int i = 0; i < 4; ++i) {
      int lin = i * 256 + t;
      int row = lin >> 5, c4 = (lin & 31) * 4;
      ushort4 o;
      o.x = f2bf(vB[i].x); o.y = f2bf(vB[i].y); o.z = f2bf(vB[i].z); o.w = f2bf(vB[i].w);
      *(ushort4*)&Bs[bufi][row * 128 + (c4 ^ ((row & 7) << 3))] = o;
    }
  };
  auto stageA = [&](int k0, int bufi) {
#pragma unroll
    for (int i = 0; i < 4; ++i) {
      int sbase = i * 256 + w * 64;
      int s = sbase + l;
      int row = s >> 4;
      int scol = ((s & 15) ^ (row & 7)) * 8;
      gload_lds16(A + (size_t)row * DIM + k0 + scol, &As[bufi][sbase * 8]);
    }
  };
  auto compute = [&](int bufi) {
#pragma unroll
    for (int kf = 0; kf < 4; ++kf) {
      int ko = kf * 32 + 8 * (l >> 4);
      int ar = w * 16 + (l & 15);
      bf16x8 af = *(const bf16x8*)&As[bufi][ar * 128 + (ko ^ rx)];
      bf16x8 b0 = *(const bf16x8*)&Bs[bufi][(l & 15) * 128 + (ko ^ rx)];
      bf16x8 b1 = *(const bf16x8*)&Bs[bufi][((l & 15) + 16) * 128 + (ko ^ rx)];
      acc0 = __builtin_amdgcn_mfma_f32_16x16x32_bf16(af, b0, acc0, 0, 0, 0);
      acc1 = __builtin_amdgcn_mfma_f32_16x16x32_bf16(af, b1, acc1, 0, 0, 0);
    }
  };

  loadB(0);
  stageA(0, 0);
  writeB(0);
  asm volatile("s_waitcnt lgkmcnt(0)" ::: "memory");

  int nk = K / 128;
  int cur = 0;
  for (int kt = 0; kt < nk - 1; ++kt) {
    loadB((kt + 1) * 128);
    stageA((kt + 1) * 128, cur ^ 1);
    asm volatile("s_waitcnt vmcnt(8)\n\ts_barrier" ::: "memory");
    compute(cur);
    writeB(cur ^ 1);
    asm volatile("s_waitcnt lgkmcnt(0)\n\ts_barrier" ::: "memory");
    cur ^= 1;
  }
  asm volatile("s_waitcnt vmcnt(0)\n\ts_barrier" ::: "memory");
  compute(cur);

  int cn = n0 + (l & 15);
  float bv0 = bias ? bias[cn] : 0.f;
  float bv1 = bias ? bias[cn + 16] : 0.f;
#pragma unroll
  for (int r = 0; r < 4; ++r) {
    int m = w * 16 + (l >> 4) * 4 + r;
    C[(size_t)m * N + cn] = acc0[r] + bv0;
    C[(size_t)m * N + cn + 16] = acc1[r] + bv1;
  }
}

// ---------------- big fused score GEMM: 8-phase 256x256 (R6/R8, verified) ----
#define READ_A(MH)                                                              \
  do {                                                                          \
    _Pragma("unroll") for (int mf = 0; mf < 4; ++mf)                            \
    _Pragma("unroll") for (int kk = 0; kk < 2; ++kk) {                          \
      int row_ = wm * 128 + (MH) * 64 + mf * 16 + lm;                           \
      fa[mf][kk] = *(const bf16x8*)&As[ct][row_ * 64 + ((kk * 32 + 8 * lq) ^ rx)]; \
    }                                                                           \
  } while (0)
#define READ_B(NH)                                                              \
  do {                                                                          \
    _Pragma("unroll") for (int nf = 0; nf < 2; ++nf)                            \
    _Pragma("unroll") for (int kk = 0; kk < 2; ++kk) {                          \
      int row_ = wn * 64 + (NH) * 32 + nf * 16 + lm;                            \
      fb[NH][nf][kk] = *(const bf16x8*)&Bs[ct][row_ * 64 + ((kk * 32 + 8 * lq) ^ rx)]; \
    }                                                                           \
  } while (0)
#define MFMA_Q(MH, NH)                                                          \
  do {                                                                          \
    __builtin_amdgcn_s_setprio(1);                                              \
    _Pragma("unroll") for (int mf = 0; mf < 4; ++mf)                            \
    _Pragma("unroll") for (int nf = 0; nf < 2; ++nf)                            \
    _Pragma("unroll") for (int kk = 0; kk < 2; ++kk)                            \
        acc[(MH) * 4 + mf][(NH) * 2 + nf] = __builtin_amdgcn_mfma_f32_16x16x32_bf16( \
            fa[mf][kk], fb[NH][nf][kk], acc[(MH) * 4 + mf][(NH) * 2 + nf], 0, 0, 0); \
    __builtin_amdgcn_s_setprio(0);                                              \
  } while (0)

__global__ void __launch_bounds__(512, 2) k_score(
    const unsigned short* __restrict__ encb, const unsigned short* __restrict__ w1mat,
    const float* __restrict__ js, const float* __restrict__ w1bias,
    const float* __restrict__ vw, float* __restrict__ att_l) {
  __shared__ unsigned short As[2][256 * 64];  // 2 x 32 KB
  __shared__ unsigned short Bs[2][256 * 64];  // 2 x 32 KB
  int tid = threadIdx.x;
  int lane = tid & 63, wid = tid >> 6;
  int wm = wid >> 2, wn = wid & 3;   // 2 x 4 wave grid
  int lm = lane & 15, lq = lane >> 4;
  int rx = (lane & 7) << 3;          // read-side XOR (elems)

  int wg = blockIdx.x;               // 512 blocks (%8==0, bijective)
  int swz = (wg & 7) * 64 + (wg >> 3);
  int m0 = (swz >> 2) * 256;         // XCD i owns m-tiles [i*16,(i+1)*16)
  int n0 = (swz & 3) * 256;          // n fastest -> A-tiles L2-shared in XCD

  const unsigned short* pa = encb + (size_t)m0 * DIM;
  const unsigned short* pb = w1mat + (size_t)n0 * DIM;

  f32x4 acc[8][4] = {};
  bf16x8 fa[4][2];       // current A half (mh), [mf][kk]
  bf16x8 fb[2][2][2];    // both B halves,   [nh][nf][kk]

  auto stageA = [&](int kt, int h, int bufi) {
#pragma unroll
    for (int i = 0; i < 2; ++i) {
      int rowbase = i * 128 + h * 64 + wid * 8;   // wave-uniform
      int row = rowbase + (lane >> 3);
      int scol = ((lane & 7) ^ (row & 7)) * 8;
      gload_lds16(pa + (size_t)row * DIM + kt * 64 + scol, &As[bufi][rowbase * 64]);
    }
  };
  auto stageB = [&](int kt, int h, int bufi) {
#pragma unroll
    for (int i = 0; i < 2; ++i) {
      int j0 = i * 64 + wid * 8;
      int rowbase = (j0 >> 5) * 64 + h * 32 + (j0 & 31);  // wave-uniform
      int row = rowbase + (lane >> 3);
      int scol = ((lane & 7) ^ (row & 7)) * 8;
      gload_lds16(pb + (size_t)row * DIM + kt * 64 + scol, &Bs[bufi][rowbase * 64]);
    }
  };

  // prologue: K-tile 0 -> buf 0, in consumption order a0,b0,b1,a1 (8 loads)
  stageA(0, 0, 0);
  stageB(0, 0, 0);
  stageB(0, 1, 0);
  stageA(0, 1, 0);
  asm volatile("s_waitcnt vmcnt(4)\n\ts_barrier" ::: "memory");  // a0,b0 landed

  for (int t = 0; t < 15; ++t) {
    const int ct = t & 1;
    // P1: reads A0,B0 (covered by prev P4 wait); stage a0'(t+1)
    READ_A(0); READ_B(0);
    stageA(t + 1, 0, ct ^ 1);
    asm volatile("s_waitcnt vmcnt(4)\n\ts_barrier" ::: "memory");  // b1(t) landed
    MFMA_Q(0, 0);
    asm volatile("s_barrier" ::: "memory");
    // P2: reads B1; stage b0'(t+1)
    READ_B(1);
    stageB(t + 1, 0, ct ^ 1);
    asm volatile("s_waitcnt vmcnt(4)\n\ts_barrier" ::: "memory");  // a1(t) landed
    MFMA_Q(0, 1);
    asm volatile("s_barrier" ::: "memory");
    // P3: reads A1; stage b1'(t+1); no vmcnt (P4 reads nothing)
    READ_A(1);
    stageB(t + 1, 1, ct ^ 1);
    asm volatile("s_barrier" ::: "memory");
    MFMA_Q(1, 1);
    asm volatile("s_barrier" ::: "memory");
    // P4: stage a1'(t+1)
    stageA(t + 1, 1, ct ^ 1);
    asm volatile("s_waitcnt vmcnt(4)\n\ts_barrier" ::: "memory");  // a0',b0' landed
    MFMA_Q(1, 0);
    asm volatile("s_barrier" ::: "memory");
  }
  {  // t = 15, no staging; drain 4 -> 2 -> 0
    const int ct = 1;
    READ_A(0); READ_B(0);
    asm volatile("s_waitcnt vmcnt(2)\n\ts_barrier" ::: "memory");  // b1 landed
    MFMA_Q(0, 0);
    asm volatile("s_barrier" ::: "memory");
    READ_B(1);
    asm volatile("s_waitcnt vmcnt(0)\n\ts_barrier" ::: "memory");  // a1 landed
    MFMA_Q(0, 1);
    asm volatile("s_barrier" ::: "memory");
    READ_A(1);
    MFMA_Q(1, 1);
    MFMA_Q(1, 0);
  }

  // fused epilogue: psum over e, 16-lane shuffle reduce, atomic into att_l
  int b = m0 >> 9;  // 256-row tile lies within one batch block (512 rows)
  const float* jrow = js + b * DIM;
  float jvv[4], vvv[4];
#pragma unroll
  for (int nj = 0; nj < 4; ++nj) {
    int e = n0 + wn * 64 + nj * 16 + lm;
    jvv[nj] = jrow[e] + w1bias[e];
    vvv[nj] = vw[e];
  }
#pragma unroll
  for (int mi = 0; mi < 8; ++mi) {
    float psum[4] = {0.f, 0.f, 0.f, 0.f};
#pragma unroll
    for (int nj = 0; nj < 4; ++nj)
#pragma unroll
      for (int r = 0; r < 4; ++r)
        psum[r] += tanh_fast(acc[mi][nj][r] + jvv[nj]) * vvv[nj];
#pragma unroll
    for (int r = 0; r < 4; ++r) {
      float s = psum[r];
      s += __shfl_xor(s, 1);
      s += __shfl_xor(s, 2);
      s += __shfl_xor(s, 4);
      s += __shfl_xor(s, 8);
      if (lm == 0)
        atomicAdd(&att_l[m0 + wm * 128 + mi * 16 + lq * 4 + r], s);
    }
  }
}
#undef READ_A
#undef READ_B
#undef MFMA_Q

// ---------------- LSTM pointwise + residual, + softmax (blocks 256-319) ------
__global__ void __launch_bounds__(256) k_lstm(
    const float* __restrict__ gates, const float* __restrict__ bih,
    const float* __restrict__ bhh, const float* __restrict__ c,
    const float* __restrict__ emb_f, float* __restrict__ out_h,
    float* __restrict__ out_c, unsigned short* __restrict__ out_b,
    const float* __restrict__ att_l, float* __restrict__ att) {
  if (blockIdx.x >= 256) {  // softmax over s (512) for batch row b, 256 threads
    __shared__ float red[8];
    int b = blockIdx.x - 256;
    int t = threadIdx.x;
    float v0 = att_l[b * SEQ + t];
    float v1 = att_l[b * SEQ + t + 256];
    float m = fmaxf(v0, v1);
#pragma unroll
    for (int o = 32; o; o >>= 1) m = fmaxf(m, __shfl_xor(m, o));
    if ((t & 63) == 0) red[t >> 6] = m;
    __syncthreads();
    m = fmaxf(fmaxf(red[0], red[1]), fmaxf(red[2], red[3]));
    float e0 = __expf(v0 - m), e1 = __expf(v1 - m);
    float s = e0 + e1;
#pragma unroll
    for (int o = 32; o; o >>= 1) s += __shfl_xor(s, o);
    __syncthreads();
    if ((t & 63) == 0) red[4 + (t >> 6)] = s;
    __syncthreads();
    s = red[4] + red[5] + red[6] + red[7];
    att[b * SEQ + t] = e0 / s;
    att[b * SEQ + t + 256] = e1 / s;
    return;
  }
  int t = blockIdx.x * 256 + threadIdx.x;  // 65536
  int b = t >> 10, d = t & 1023;
  const float* g = gates + b * 4 * DIM;
  float ig = g[d] + bih[d] + bhh[d];
  float fg = g[DIM + d] + bih[DIM + d] + bhh[DIM + d];
  float gg = g[2 * DIM + d] + bih[2 * DIM + d] + bhh[2 * DIM + d];
  float og = g[3 * DIM + d] + bih[3 * DIM + d] + bhh[3 * DIM + d];
  float cn = sigmf(fg) * c[t] + sigmf(ig) * tanh_fast(gg);
  float hn = sigmf(og) * tanh_fast(cn);
  out_h[t] = hn;
  out_c[t] = cn;
  out_b[t] = f2bf(hn + emb_f[t]);  // residual, bf16 for logits GEMM
}

// -----------------------------------------------------------------------------
extern "C" void kernel_launch(void* const* d_in, const int* in_sizes, int n_in,
                              void* d_out, int out_size, void* d_ws, size_t ws_size,
                              hipStream_t stream) {
  const int* x = (const int*)d_in[0];
  const float* h = (const float*)d_in[1];
  const float* c = (const float*)d_in[2];
  const float* enc = (const float*)d_in[3];
  const float* Femb = (const float*)d_in[4];
  const float* W1w = (const float*)d_in[5];
  const float* W1b = (const float*)d_in[6];
  const float* W2w = (const float*)d_in[7];
  const float* W2b = (const float*)d_in[8];
  const float* Vw = (const float*)d_in[9];
  // d_in[10] = V_b: softmax-invariant, unused
  const float* Wih = (const float*)d_in[11];
  const float* Whh = (const float*)d_in[12];
  const float* bih = (const float*)d_in[13];
  const float* bhh = (const float*)d_in[14];
  const float* fcw = (const float*)d_in[15];
  const float* fcb = (const float*)d_in[16];

  float* out_logits = (float*)d_out;
  float* out_h = out_logits + (size_t)BATCH * VOCAB;
  float* out_c = out_h + BATCH * DIM;
  float* out_att = out_c + BATCH * DIM;

  char* p = (char*)d_ws;
  unsigned short* enc_b = (unsigned short*)p; p += (size_t)M_SC * DIM * 2;
  unsigned short* w1_b = (unsigned short*)p;  p += (size_t)DIM * DIM * 2;
  float* att_l = (float*)p;                   p += (size_t)M_SC * 4;
  float* js = (float*)p;                      p += (size_t)BATCH * DIM * 4;
  float* emb_f = (float*)p;                   p += (size_t)BATCH * DIM * 4;
  unsigned short* eh_b = (unsigned short*)p;  p += (size_t)BATCH * 2 * DIM * 2;
  unsigned short* h_b = (unsigned short*)p;   p += (size_t)BATCH * DIM * 2;
  float* gates = (float*)p;                   p += (size_t)BATCH * 4 * DIM * 4;
  unsigned short* out_b = (unsigned short*)p; p += (size_t)BATCH * DIM * 2;

  hipLaunchKernelGGL(k_prep, dim3(2048), dim3(256), 0, stream, enc, W1w, enc_b, w1_b,
                     att_l, x, Femb, h, emb_f, eh_b, h_b);
  // one launch: gates (blocks 0-255) + js (blocks 256-319)
  //   gates = [emb|h] @ [W_ih|W_hh]^T -> [64][4096] (biases added in k_lstm)
  //   js    = h @ W2^T + W2_b         -> [64][1024]
  hipLaunchKernelGGL(k_skinny, dim3(256 + 64), dim3(256), 0, stream,
                     eh_b, 2 * DIM, Wih, Whh, DIM, (const float*)nullptr,
                     gates, 4 * DIM, 2 * DIM,
                     256,
                     h_b, DIM, W2w, W2w, DIM, W2b, js, DIM, DIM);
  // fused attention scores -> att_l (8-phase 256x256)
  hipLaunchKernelGGL(k_score, dim3(512), dim3(512), 0, stream,
                     enc_b, w1_b, js, W1b, Vw, att_l);
  // lstm pointwise (blocks 0-255) + softmax (blocks 256-319)
  hipLaunchKernelGGL(k_lstm, dim3(320), dim3(256), 0, stream,
                     gates, bih, bhh, c, emb_f, out_h, out_c, out_b, att_l, out_att);
  // logits = (h_new + emb) @ fc_w^T + fc_b  (N-tile 32)
  hipLaunchKernelGGL(k_skinny32, dim3(VOCAB / 32), dim3(256), 0, stream,
                     out_b, fcw, fcb, out_logits, VOCAB, DIM);
}